// Round 6
// baseline (226.574 us; speedup 1.0000x reference)
//
#include <hip/hip_runtime.h>
#include <cstdint>

#define EPSF 1e-5f

typedef __attribute__((ext_vector_type(8))) short short8;
typedef __attribute__((ext_vector_type(4))) float f32x4;
typedef __attribute__((ext_vector_type(4))) unsigned int u32x4;

// RNE float -> bf16 bits (inputs always finite here)
__device__ inline uint32_t bf16rne(float x) {
    uint32_t u = __builtin_bit_cast(uint32_t, x);
    return (u + 0x7fffu + ((u >> 16) & 1u)) >> 16;
}
__device__ inline float bf16f(uint32_t b) {
    return __builtin_bit_cast(float, b << 16);
}

// ============================== prep ==============================
// blocks [0,129): wfcb pack via ballot-transpose — wave = one j row
//   (j = blk*4 + wid), lane = (c, pos-parity). One strided dword load +
//   one __ballot per 2 positions; row L1-resident after first taps.
// blocks [129,167): id-indexed small sections.
__global__ __launch_bounds__(256) void prep_kernel(
    const float* __restrict__ w2, const float* __restrict__ wfc,
    const float* __restrict__ g3, const float* __restrict__ be3,
    const float* __restrict__ m3, const float* __restrict__ v3,
    const float* __restrict__ wlast,
    const float* __restrict__ w0, const float* __restrict__ b0,
    const float* __restrict__ g1, const float* __restrict__ be1,
    const float* __restrict__ m1, const float* __restrict__ v1,
    uint32_t* __restrict__ w2bits, uint32_t* __restrict__ wfcb,
    float* __restrict__ inv3p, float* __restrict__ sh3p, float* __restrict__ wlt,
    uint32_t* __restrict__ bfrag, float2* __restrict__ bn1c)
{
    const int tid = threadIdx.x;
    if (blockIdx.x < 129) {               // wfcb: [pos][j] bit=c
        const int wid = tid >> 6, lane = tid & 63;
        const int j = blockIdx.x * 4 + wid;          // 0..515
        const int c = lane & 31, pp = lane >> 5;
        const float* row = wfc + j * 1152 + c * 36;
        #pragma unroll
        for (int i = 0; i < 18; i++) {
            int pos = 2 * i + pp;
            float v = row[pos];
            unsigned long long mb = __ballot(v < 0.f);
            if (lane == 0)  wfcb[(2 * i) * 576 + j]     = (uint32_t)mb;
            if (lane == 32) wfcb[(2 * i + 1) * 576 + j] = (uint32_t)(mb >> 32);
        }
        return;
    }
    int id = (blockIdx.x - 129) * 256 + tid;
    if (id < 288) {                       // w2 sign pack: [co][tap] bit=ci
        int co = id / 9, r = id % 9;
        uint32_t b = 0;
        for (int ci = 0; ci < 32; ci++)
            b |= (uint32_t)(w2[(co * 32 + ci) * 9 + r] < 0.f) << ci;
        w2bits[id] = b;
        return;
    }
    id -= 288;
    if (id < 576) {                       // BN3 (pad -> 0)
        float iv = 0.f, sh = 0.f;
        if (id < 516) {
            iv = g3[id] / sqrtf(__fadd_rn(v3[id], EPSF));
            sh = __fsub_rn(be3[id], __fmul_rn(m3[id], iv));
        }
        inv3p[id] = iv; sh3p[id] = sh;
        return;
    }
    id -= 576;
    if (id < 5760) {                      // wlt [k*576 + j]
        int k = id / 576, j = id % 576;
        wlt[id] = (j < 516) ? wlast[k * 516 + j] : 0.f;
        return;
    }
    id -= 5760;
    if (id < 768) {                       // convA B-fragments, per-lane layout
        int L = id / 12, r = id % 12;
        int nt = r / 6, s = (r % 6) / 2, h = r & 1;
        int g = L >> 4, n = L & 15;
        int tap = 4 * s + g;
        uint32_t d[4] = {0, 0, 0, 0};
        if (tap < 9) {
            int co = nt * 16 + n;
            for (int j2 = 0; j2 < 4; j2++) {
                float wa = w0[co * 72 + (2 * j2) * 9 + tap];
                float wb = w0[co * 72 + (2 * j2 + 1) * 9 + tap];
                uint32_t ha = bf16rne(wa), hb = bf16rne(wb);
                uint32_t va, vb;
                if (h == 0) { va = ha; vb = hb; }
                else { va = bf16rne(wa - bf16f(ha)); vb = bf16rne(wb - bf16f(hb)); }
                d[j2] = va | (vb << 16);
            }
        }
        *(u32x4*)(bfrag + id * 4) = (u32x4){d[0], d[1], d[2], d[3]};
        return;
    }
    id -= 768;
    if (id < 32) {                        // BN1 folded constants
        float iv = g1[id] / sqrtf(__fadd_rn(v1[id], EPSF));
        float sh = __fsub_rn(be1[id], __fmul_rn(m1[id], iv));
        float off = __fadd_rn(__fmul_rn(b0[id], iv), sh);
        bn1c[id] = make_float2(iv, off);
        return;
    }
    id -= 32;
    if (id < 2160) {                      // wfcb pad columns j in [516,576)
        int p = id / 60, j = 516 + id % 60;
        wfcb[p * 576 + j] = 0u;
    }
}

// ================== conv1 fp64 sign recheck (rare) ==================
__device__ __noinline__ bool recheck_sign(const float* __restrict__ xim,
                                          const float* __restrict__ w0,
                                          int py, int px, int co,
                                          float ivc, float offc)
{
    double ad = 0.0;
    for (int ci = 0; ci < 8; ci++)
        for (int ky = 0; ky < 3; ky++)
            for (int kx = 0; kx < 3; kx++)
                ad = fma((double)xim[ci * 256 + (py + ky) * 16 + px + kx],
                         (double)w0[co * 72 + ci * 9 + ky * 3 + kx], ad);
    return (ad * (double)ivc + (double)offc) < 0.0;
}

// ============================== convA ==============================
// conv1 via split-bf16 MFMA implicit GEMM (layout validated R4/R5).
// Block = 256 thr = 4 waves = 2 images, TWO waves per image: each wave
// stages half the image (2x8 loads) and computes half the 13 M-tiles —
// halves per-wave latency vs R5's 1-wave/image and lifts TLP (LDS cap:
// 18.4KB/block -> 8 blocks/CU = 32 waves/CU).
__global__ __launch_bounds__(256, 4) void convA(
    const float* __restrict__ x, const float* __restrict__ w0,
    const uint32_t* __restrict__ bfrag, const float2* __restrict__ bn1c,
    uint32_t* __restrict__ s1bits)
{
    __shared__ __align__(16) char simg[2][9216];

    const int t = threadIdx.x;
    const int wv = t >> 6, lane = t & 63;
    const int ilocal = wv >> 1;           // image within block
    const int w01 = wv & 1;               // wave within image
    const int img = blockIdx.x * 2 + ilocal;
    const float* xim = x + img * 2048;
    char* hib = simg[ilocal];
    char* lob = simg[ilocal] + 4608;

    const int g = lane >> 4;              // quad
    const int n = lane & 15;

    // ---- B fragments: 12 x 16B per lane, precomputed in prep (L2-hot)
    short8 Bh[2][3], Bl[2][3];
    {
        const uint32_t* bb = bfrag + lane * 48;
        #pragma unroll
        for (int nt = 0; nt < 2; nt++)
            #pragma unroll
            for (int s = 0; s < 3; s++) {
                Bh[nt][s] = *(const short8*)(bb + (nt * 6 + s * 2) * 4);
                Bl[nt][s] = *(const short8*)(bb + (nt * 6 + s * 2 + 1) * 4);
            }
    }
    const float2 bnA = bn1c[n], bnB = bn1c[16 + n];

    // ---- stage this wave's half of the image (128 positions)
    #pragma unroll
    for (int q = 0; q < 2; q++) {
        int pos = w01 * 128 + 64 * q + lane;
        float v[8];
        #pragma unroll
        for (int ci = 0; ci < 8; ci++) v[ci] = xim[ci * 256 + pos];
        uint32_t hw[4], lw[4];
        #pragma unroll
        for (int j2 = 0; j2 < 4; j2++) {
            float a = v[2 * j2], b = v[2 * j2 + 1];
            uint32_t ha = bf16rne(a), hb = bf16rne(b);
            uint32_t la = bf16rne(a - bf16f(ha)), lb = bf16rne(b - bf16f(hb));
            hw[j2] = ha | (hb << 16);
            lw[j2] = la | (lb << 16);
        }
        *(u32x4*)(hib + pos * 16) = (u32x4){hw[0], hw[1], hw[2], hw[3]};
        *(u32x4*)(lob + pos * 16) = (u32x4){lw[0], lw[1], lw[2], lw[3]};
    }
    if (w01 == 1 && lane < 32) {          // zero guard slots 256..287
        *(u32x4*)(hib + (256 + lane) * 16) = (u32x4){0, 0, 0, 0};
        *(u32x4*)(lob + (256 + lane) * 16) = (u32x4){0, 0, 0, 0};
    }

    // per-lane A LDS byte offsets per K-step (tap window); pad-taps -> 0 (B=0)
    int koff[3];
    #pragma unroll
    for (int s = 0; s < 3; s++) {
        int tap = 4 * s + g;
        koff[s] = (tap < 9) ? ((tap / 3) * 16 + (tap % 3)) * 16 : 0;
    }

    __syncthreads();

    uint32_t* outb = s1bits + img * 196;
    const int tstart = w01 ? 7 : 0, tend = w01 ? 13 : 7;

    for (int tile = tstart; tile < tend; ++tile) {
        int posA = tile * 16 + n;
        int pyA = posA / 14, pxA = posA - pyA * 14;
        int sl = (pyA * 16 + pxA) * 16;

        f32x4 acc0 = {0.f, 0.f, 0.f, 0.f}, acc1 = {0.f, 0.f, 0.f, 0.f};
        #pragma unroll
        for (int s = 0; s < 3; s++) {
            short8 Ah = *(const short8*)(hib + sl + koff[s]);
            short8 Al = *(const short8*)(lob + sl + koff[s]);
            acc0 = __builtin_amdgcn_mfma_f32_16x16x32_bf16(Al, Bh[0][s], acc0, 0, 0, 0);
            acc0 = __builtin_amdgcn_mfma_f32_16x16x32_bf16(Ah, Bl[0][s], acc0, 0, 0, 0);
            acc0 = __builtin_amdgcn_mfma_f32_16x16x32_bf16(Ah, Bh[0][s], acc0, 0, 0, 0);
            acc1 = __builtin_amdgcn_mfma_f32_16x16x32_bf16(Al, Bh[1][s], acc1, 0, 0, 0);
            acc1 = __builtin_amdgcn_mfma_f32_16x16x32_bf16(Ah, Bl[1][s], acc1, 0, 0, 0);
            acc1 = __builtin_amdgcn_mfma_f32_16x16x32_bf16(Ah, Bh[1][s], acc1, 0, 0, 0);
        }

        // epilogue: C/D row = 4*g + r (pos), col = n (co / co+16)
        #pragma unroll
        for (int r = 0; r < 4; r++) {
            int pos = tile * 16 + 4 * g + r;
            float yv0 = fmaf(acc0[r], bnA.x, bnA.y);
            float yv1 = fmaf(acc1[r], bnB.x, bnB.y);
            bool bit0, bit1;
            if (__builtin_expect(pos < 196 && fabsf(yv0) < 3e-4f, 0)) {
                int py = pos / 14, px = pos - py * 14;
                bit0 = recheck_sign(xim, w0, py, px, n, bnA.x, bnA.y);
            } else bit0 = (yv0 < 0.f);
            if (__builtin_expect(pos < 196 && fabsf(yv1) < 3e-4f, 0)) {
                int py = pos / 14, px = pos - py * 14;
                bit1 = recheck_sign(xim, w0, py, px, 16 + n, bnB.x, bnB.y);
            } else bit1 = (yv1 < 0.f);
            unsigned long long m0 = __ballot(bit0);
            unsigned long long m1 = __ballot(bit1);
            uint32_t word = (uint32_t)((m0 >> (16 * g)) & 0xffffull)
                          | ((uint32_t)((m1 >> (16 * g)) & 0xffffull) << 16);
            if (n == 0 && pos < 196) outb[pos] = word;
        }
    }
}

// ============================== convBF ==============================
// FUSED: binary conv2 + BN2 + hardtanh + maxpool + sign  ->  LDS fcin
//        -> binary FC + BN3 + hardtanh + final 516x10 linear.
// Block = 256 thr = 4 waves = 8 images. Phase 1: wave computes 2 images
// (36 words each, pos-major bit=c) into LDS. Phase 2: wave = 2 batches
// of the FC pipeline (identical numerics to the passing fcC).
__global__ __launch_bounds__(256) void convBF(
    const uint32_t* __restrict__ s1bits, const uint32_t* __restrict__ w2bits,
    const float* __restrict__ g2, const float* __restrict__ be2,
    const float* __restrict__ m2, const float* __restrict__ v2,
    const uint32_t* __restrict__ wfcb,
    const float* __restrict__ inv3p, const float* __restrict__ sh3p,
    const float* __restrict__ wlt, const float* __restrict__ blast,
    float* __restrict__ out)
{
    __shared__ uint32_t s1l[8][196];
    __shared__ uint32_t l_in[288];        // 8 images x 36 words
    const int t = threadIdx.x, wid = t >> 6, lane = t & 63;

    for (int i = t; i < 1568; i += 256)
        ((uint32_t*)s1l)[i] = s1bits[blockIdx.x * 1568 + i];

    const int c = lane & 31, h = lane >> 5;
    uint32_t wr[9];
    #pragma unroll
    for (int k = 0; k < 9; k++) wr[k] = w2bits[c * 9 + k];
    float ivv = g2[c] / sqrtf(__fadd_rn(v2[c], EPSF));
    float shv = __fsub_rn(be2[c], __fmul_rn(m2[c], ivv));
    __syncthreads();

    // ---- phase 1: conv2 for 2 images per wave
    for (int rep = 0; rep < 2; rep++) {
        const int iml = wid * 2 + rep;
        const uint32_t* s1w = s1l[iml];
        uint32_t* outp = &l_in[iml * 36];

        for (int yy = 0; yy < 3; yy++) {
            const int y2 = yy + 3 * h;
            const int rbase = 2 * y2 * 14;
            uint32_t win[4][4];
            #pragma unroll
            for (int rr = 0; rr < 4; rr++) {
                uint2 a = *(const uint2*)&s1w[rbase + rr * 14];
                uint2 b = *(const uint2*)&s1w[rbase + rr * 14 + 2];
                win[rr][0] = a.x; win[rr][1] = a.y; win[rr][2] = b.x; win[rr][3] = b.y;
            }
            for (int x2 = 0; x2 < 6; x2++) {
                if (x2 > 0) {
                    #pragma unroll
                    for (int rr = 0; rr < 4; rr++) {
                        win[rr][0] = win[rr][2]; win[rr][1] = win[rr][3];
                        uint2 b = *(const uint2*)&s1w[rbase + rr * 14 + 2 * x2 + 2];
                        win[rr][2] = b.x; win[rr][3] = b.y;
                    }
                }
                int mx = -10000;
                #pragma unroll
                for (int dy = 0; dy < 2; dy++)
                    #pragma unroll
                    for (int dx = 0; dx < 2; dx++) {
                        int p = 0;
                        #pragma unroll
                        for (int ky = 0; ky < 3; ky++)
                            #pragma unroll
                            for (int kx = 0; kx < 3; kx++)
                                p += __popc(win[dy + ky][dx + kx] ^ wr[ky * 3 + kx]);
                        mx = max(mx, 288 - 2 * p);
                    }
                float yv = __fadd_rn(__fmul_rn((float)mx, ivv), shv);
                unsigned long long mb = __ballot(yv < 0.f);
                int pos = y2 * 6 + x2;
                if (lane == 0)  outp[pos] = (uint32_t)mb;
                if (lane == 32) outp[pos] = (uint32_t)(mb >> 32);
            }
        }
    }
    __syncthreads();

    // ---- phase 2: FC for 2 batches per wave
    const int b0i = blockIdx.x * 8 + wid * 2;
    const uint32_t* in0 = &l_in[wid * 72];

    int pc0[9], pc1[9];
    #pragma unroll
    for (int q = 0; q < 9; q++) { pc0[q] = 0; pc1[q] = 0; }

    for (int w = 0; w < 36; w++) {
        uint32_t i0 = in0[w], i1 = in0[36 + w];
        const uint32_t* wf = wfcb + w * 576 + lane;
        #pragma unroll
        for (int q = 0; q < 9; q++) {
            uint32_t f = wf[q * 64];
            pc0[q] += __popc(i0 ^ f);
            pc1[q] += __popc(i1 ^ f);
        }
    }

    float oa[2][10];
    #pragma unroll
    for (int b = 0; b < 2; b++)
        #pragma unroll
        for (int k = 0; k < 10; k++) oa[b][k] = 0.f;

    #pragma unroll
    for (int q = 0; q < 9; q++) {
        int j = lane + 64 * q;
        float iv3 = inv3p[j], sh3 = sh3p[j];
        float t0 = fminf(1.f, fmaxf(-1.f, __fadd_rn(__fmul_rn((float)(1152 - 2 * pc0[q]), iv3), sh3)));
        float t1 = fminf(1.f, fmaxf(-1.f, __fadd_rn(__fmul_rn((float)(1152 - 2 * pc1[q]), iv3), sh3)));
        #pragma unroll
        for (int k = 0; k < 10; k++) {
            float wvv = wlt[k * 576 + j];
            oa[0][k] = fmaf(t0, wvv, oa[0][k]);
            oa[1][k] = fmaf(t1, wvv, oa[1][k]);
        }
    }

    #pragma unroll
    for (int m = 1; m < 64; m <<= 1)
        #pragma unroll
        for (int b = 0; b < 2; b++)
            #pragma unroll
            for (int k = 0; k < 10; k++)
                oa[b][k] += __shfl_xor(oa[b][k], m, 64);

    if (lane == 0) {
        for (int b = 0; b < 2; b++)
            for (int k = 0; k < 10; k++)
                out[(b0i + b) * 10 + k] = oa[b][k] + blast[k];
    }
}

// ============================== launch ==============================
extern "C" void kernel_launch(void* const* d_in, const int* in_sizes, int n_in,
                              void* d_out, int out_size, void* d_ws, size_t ws_size,
                              hipStream_t stream)
{
    (void)in_sizes; (void)n_in; (void)out_size; (void)ws_size;
    const float* x     = (const float*)d_in[0];
    const float* w0    = (const float*)d_in[1];
    const float* b0    = (const float*)d_in[2];
    const float* g1    = (const float*)d_in[3];
    const float* be1   = (const float*)d_in[4];
    const float* m1    = (const float*)d_in[5];
    const float* v1    = (const float*)d_in[6];
    const float* w2    = (const float*)d_in[7];
    const float* g2    = (const float*)d_in[8];
    const float* be2   = (const float*)d_in[9];
    const float* m2    = (const float*)d_in[10];
    const float* v2    = (const float*)d_in[11];
    const float* wfc   = (const float*)d_in[12];
    const float* g3    = (const float*)d_in[13];
    const float* be3   = (const float*)d_in[14];
    const float* m3    = (const float*)d_in[15];
    const float* v3    = (const float*)d_in[16];
    const float* wlast = (const float*)d_in[17];
    const float* blast = (const float*)d_in[18];

    char* ws = (char*)d_ws;
    uint32_t* s1bits = (uint32_t*)(ws);                 // 8192*196*4 = 6,422,528 B
    uint32_t* w2bits = (uint32_t*)(ws + 6422528);       // 288*4
    uint32_t* wfcb   = (uint32_t*)(ws + 6423680);       // 36*576*4 = 82,944 B
    float*    inv3p  = (float*)(ws + 6506624);          // 576*4
    float*    sh3p   = (float*)(ws + 6508928);          // 576*4
    float*    wlt    = (float*)(ws + 6511232);          // 10*576*4 = 23,040 B
    uint32_t* bfrag  = (uint32_t*)(ws + 6534272);       // 768*16 = 12,288 B
    float2*   bn1c   = (float2*)(ws + 6546560);         // 32*8 = 256 B

    prep_kernel<<<167, 256, 0, stream>>>(w2, wfc, g3, be3, m3, v3, wlast,
                                         w0, b0, g1, be1, m1, v1,
                                         w2bits, wfcb, inv3p, sh3p, wlt,
                                         bfrag, bn1c);
    convA<<<4096, 256, 0, stream>>>(x, w0, bfrag, bn1c, s1bits);
    convBF<<<1024, 256, 0, stream>>>(s1bits, w2bits, g2, be2, m2, v2,
                                     wfcb, inv3p, sh3p, wlt, blast, (float*)d_out);
}